// Round 1
// baseline (49.999 us; speedup 1.0000x reference)
//
#include <hip/hip_runtime.h>

// Quantum kernel method: 8 qubits, DIM=256, DEPTH=2, B=16384.
// One wave (64 lanes) per batch element; lane owns amplitudes i = lane*4+k.
// Qubit q lives on bit (7-q): q=0..5 -> lane bits (shfl_xor), q=6,7 -> in-lane.
// Layer-0 RY+CNOT-perm fused as product-state evaluated at permuted index.
// RZ layers as single phase accumulation + sincos per amplitude.

__global__ __launch_bounds__(256) void qkm_kernel(
    const float* __restrict__ x, const float* __restrict__ y,
    const float* __restrict__ params, float* __restrict__ out, int B)
{
    __shared__ float2 buf[4][256];   // 8 KB per block, one 256-amp buffer per wave

    const int lane = (int)(threadIdx.x & 63u);
    const int w    = (int)(threadIdx.x >> 6u);
    int b = (int)blockIdx.x * 4 + w;
    if (b >= B) b = B - 1;           // clamp (no early return: barriers below)

    // CNOT-ladder permutation P: state_new[i] = state_old[P(i)]
    // P = g(0,1) o g(1,2) o ... o g(6,7) applied innermost-first,
    // g(c,t)(j) = j ^ (((j>>(7-c))&1) << (7-t))
    int jp[4];
#pragma unroll
    for (int k = 0; k < 4; ++k) {
        int j = (lane << 2) | k;
#pragma unroll
        for (int q = 6; q >= 0; --q)
            j ^= ((j >> (7 - q)) & 1) << (6 - q);
        jp[k] = j;
    }

    // half params for the two RZ layers
    float hp0[8], hp1[8];
#pragma unroll
    for (int q = 0; q < 8; ++q) {
        hp0[q] = 0.5f * params[q];
        hp1[q] = 0.5f * params[8 + q];
    }

    float sxr[4], sxi[4], syr[4], syi[4];

#pragma unroll
    for (int which = 0; which < 2; ++which) {
        const float* v = (which == 0) ? (x + (size_t)b * 8) : (y + (size_t)b * 8);

        float c[8], s[8];
#pragma unroll
        for (int q = 0; q < 8; ++q) {
            float h = 0.5f * v[q];
            s[q] = sinf(h);
            c[q] = cosf(h);
        }

        // ---- layer 0: RY product state, fused with CNOT perm ----
        // new[i] = prod_q ( bit(7-q) of P(i) ? s_q : c_q ), imag = 0
        float ar[4], ai[4];
#pragma unroll
        for (int k = 0; k < 4; ++k) {
            int j = jp[k];
            float a = 1.0f;
#pragma unroll
            for (int q = 0; q < 8; ++q)
                a *= ((j >> (7 - q)) & 1) ? s[q] : c[q];
            ar[k] = a;
            ai[k] = 0.0f;
        }

        // ---- RZ layer d=0: phi(i) = sum_q (+-) hp0[q]; state is real ----
        {
            float phl = 0.0f;
#pragma unroll
            for (int q = 0; q < 6; ++q)
                phl += ((lane >> (5 - q)) & 1) ? hp0[q] : -hp0[q];
#pragma unroll
            for (int k = 0; k < 4; ++k) {
                float phi = phl + ((k & 2) ? hp0[6] : -hp0[6])
                                + ((k & 1) ? hp0[7] : -hp0[7]);
                float sp, cp;
                sincosf(phi, &sp, &cp);
                ai[k] = ar[k] * sp;
                ar[k] = ar[k] * cp;
            }
        }

        // ---- layer 1 RY: butterflies ----
#pragma unroll
        for (int q = 0; q < 6; ++q) {
            const int   mask = 1 << (5 - q);
            const int   bit  = (lane >> (5 - q)) & 1;
            const float sg   = bit ? s[q] : -s[q];
            const float cc   = c[q];
#pragma unroll
            for (int k = 0; k < 4; ++k) {
                float pr = __shfl_xor(ar[k], mask, 64);
                float pi = __shfl_xor(ai[k], mask, 64);
                ar[k] = cc * ar[k] + sg * pr;
                ai[k] = cc * ai[k] + sg * pi;
            }
        }
        {   // q=6: bit 1 -> pairs (0,2),(1,3)
            const float c6 = c[6], s6 = s[6];
            float n0r = c6*ar[0] - s6*ar[2], n0i = c6*ai[0] - s6*ai[2];
            float n2r = s6*ar[0] + c6*ar[2], n2i = s6*ai[0] + c6*ai[2];
            float n1r = c6*ar[1] - s6*ar[3], n1i = c6*ai[1] - s6*ai[3];
            float n3r = s6*ar[1] + c6*ar[3], n3i = s6*ai[1] + c6*ai[3];
            ar[0]=n0r; ai[0]=n0i; ar[2]=n2r; ai[2]=n2i;
            ar[1]=n1r; ai[1]=n1i; ar[3]=n3r; ai[3]=n3i;
        }
        {   // q=7: bit 0 -> pairs (0,1),(2,3)
            const float c7 = c[7], s7 = s[7];
            float n0r = c7*ar[0] - s7*ar[1], n0i = c7*ai[0] - s7*ai[1];
            float n1r = s7*ar[0] + c7*ar[1], n1i = s7*ai[0] + c7*ai[1];
            float n2r = c7*ar[2] - s7*ar[3], n2i = c7*ai[2] - s7*ai[3];
            float n3r = s7*ar[2] + c7*ar[3], n3i = s7*ai[2] + c7*ai[3];
            ar[0]=n0r; ai[0]=n0i; ar[1]=n1r; ai[1]=n1i;
            ar[2]=n2r; ai[2]=n2i; ar[3]=n3r; ai[3]=n3i;
        }

        // ---- CNOT perm (layer 1) via LDS gather ----
        __syncthreads();
#pragma unroll
        for (int k = 0; k < 4; ++k)
            buf[w][(lane << 2) | k] = make_float2(ar[k], ai[k]);
        __syncthreads();
#pragma unroll
        for (int k = 0; k < 4; ++k) {
            float2 t = buf[w][jp[k]];
            ar[k] = t.x; ai[k] = t.y;
        }

        // ---- RZ layer d=1 (complex state) ----
        {
            float phl = 0.0f;
#pragma unroll
            for (int q = 0; q < 6; ++q)
                phl += ((lane >> (5 - q)) & 1) ? hp1[q] : -hp1[q];
#pragma unroll
            for (int k = 0; k < 4; ++k) {
                float phi = phl + ((k & 2) ? hp1[6] : -hp1[6])
                                + ((k & 1) ? hp1[7] : -hp1[7]);
                float sp, cp;
                sincosf(phi, &sp, &cp);
                float nr = ar[k]*cp - ai[k]*sp;
                float ni = ar[k]*sp + ai[k]*cp;
                ar[k] = nr; ai[k] = ni;
            }
        }

        if (which == 0) {
#pragma unroll
            for (int k = 0; k < 4; ++k) { sxr[k]=ar[k]; sxi[k]=ai[k]; }
        } else {
#pragma unroll
            for (int k = 0; k < 4; ++k) { syr[k]=ar[k]; syi[k]=ai[k]; }
        }
    }

    // overlap = sum_i conj(sx_i)*sy_i ; out = |overlap|^2
    float re = 0.0f, im = 0.0f;
#pragma unroll
    for (int k = 0; k < 4; ++k) {
        re += sxr[k]*syr[k] + sxi[k]*syi[k];
        im += sxr[k]*syi[k] - sxi[k]*syr[k];
    }
#pragma unroll
    for (int m = 32; m >= 1; m >>= 1) {
        re += __shfl_xor(re, m, 64);
        im += __shfl_xor(im, m, 64);
    }
    if (lane == 0) out[b] = re*re + im*im;
}

extern "C" void kernel_launch(void* const* d_in, const int* in_sizes, int n_in,
                              void* d_out, int out_size, void* d_ws, size_t ws_size,
                              hipStream_t stream) {
    const float* x      = (const float*)d_in[0];
    const float* y      = (const float*)d_in[1];
    const float* params = (const float*)d_in[2];
    float* out = (float*)d_out;
    const int B = in_sizes[0] / 8;          // 16384
    const int blocks = (B + 3) / 4;         // 4 waves (batch elems) per block
    qkm_kernel<<<blocks, 256, 0, stream>>>(x, y, params, out, B);
}

// Round 2
// 29.524 us; speedup vs baseline: 1.6935x; 1.6935x over previous
//
#include <hip/hip_runtime.h>

// Quantum kernel method: 8 qubits, DIM=256, DEPTH=2, B=16384.
// One wave per batch element; lane owns amplitudes i = lane*4+k.
// Qubit q lives on bit (7-q): q=0..5 -> lane bits (shfl_xor), q=6,7 -> in-lane.
// R2: native trig (v_sin/v_cos), RZ phase factors hoisted (param-only, shared
// between x and y), CNOT perm linearity -> shared qubit-0..5 product.

__device__ __forceinline__ float nsin(float x) { return __sinf(x); }
__device__ __forceinline__ float ncos(float x) { return __cosf(x); }

__global__ __launch_bounds__(256) void qkm_kernel(
    const float* __restrict__ x, const float* __restrict__ y,
    const float* __restrict__ params, float* __restrict__ out, int B)
{
    __shared__ float2 buf[4][256];   // one 256-amp buffer per wave

    const int lane = (int)(threadIdx.x & 63u);
    const int w    = (int)(threadIdx.x >> 6u);
    int b = (int)blockIdx.x * 4 + w;
    if (b >= B) b = B - 1;           // clamp (no early return: barriers below)

    // CNOT perm P is GF(2)-linear: P(j)_i = j_i ^ j_{i+1} (i<7), P(j)_7 = j_7.
    // jp[k] = base ^ d[k], d = {0,1,3,2} (only low 2 bits = qubits 7,6 differ).
    int base = lane << 2;
#pragma unroll
    for (int q = 6; q >= 0; --q)
        base ^= ((base >> (7 - q)) & 1) << (6 - q);
    const int b3 = base & 3;

    // half params
    float hp0[8], hp1[8];
#pragma unroll
    for (int q = 0; q < 8; ++q) {
        hp0[q] = 0.5f * params[q];
        hp1[q] = 0.5f * params[8 + q];
    }

    // ---- RZ phase factors (param-only; shared between x and y states) ----
    // phi(i) = sum_q (bit(7-q)(i) ? +hp[q] : -hp[q]); i = lane*4+k.
    // pf[k] = exp(i*(phl +- h6 +- h7)), k&2 -> +h6, k&1 -> +h7.
    float p0r[4], p0i[4], p1r[4], p1i[4];
#pragma unroll
    for (int d = 0; d < 2; ++d) {
        const float* hp = d ? hp1 : hp0;
        float phl = 0.0f;
#pragma unroll
        for (int q = 0; q < 6; ++q)
            phl += ((lane >> (5 - q)) & 1) ? hp[q] : -hp[q];
        float sl = nsin(phl), cl = ncos(phl);
        float s6 = nsin(hp[6]), c6 = ncos(hp[6]);
        float s7 = nsin(hp[7]), c7 = ncos(hp[7]);
        float cpp = c6 * c7 - s6 * s7, spp = s6 * c7 + c6 * s7;  // h6+h7
        float cpm = c6 * c7 + s6 * s7, spm = s6 * c7 - c6 * s7;  // h6-h7
        // k=0: -(h6+h7); k=1: h7-h6; k=2: h6-h7; k=3: h6+h7
        float er0 = cpp, ei0 = -spp;
        float er1 = cpm, ei1 = -spm;
        float er2 = cpm, ei2 =  spm;
        float er3 = cpp, ei3 =  spp;
        float* pr = d ? p1r : p0r;
        float* pi = d ? p1i : p0i;
        pr[0] = cl * er0 - sl * ei0;  pi[0] = sl * er0 + cl * ei0;
        pr[1] = cl * er1 - sl * ei1;  pi[1] = sl * er1 + cl * ei1;
        pr[2] = cl * er2 - sl * ei2;  pi[2] = sl * er2 + cl * ei2;
        pr[3] = cl * er3 - sl * ei3;  pi[3] = sl * er3 + cl * ei3;
    }

    float sxr[4], sxi[4], syr[4], syi[4];

#pragma unroll
    for (int which = 0; which < 2; ++which) {
        const float4* vv = (const float4*)((which == 0) ? (x + (size_t)b * 8)
                                                        : (y + (size_t)b * 8));
        float4 va = vv[0], vb = vv[1];
        float ang[8] = {va.x, va.y, va.z, va.w, vb.x, vb.y, vb.z, vb.w};

        float c[8], s[8];
#pragma unroll
        for (int q = 0; q < 8; ++q) {
            float h = 0.5f * ang[q];
            s[q] = nsin(h);
            c[q] = ncos(h);
        }

        // ---- layer 0 RY product state fused with CNOT perm ----
        // amplitude at jp[k]: product over q0..5 depends only on base (high 6
        // bits); q6,q7 factors selected by (base&3)^d[k].
        float A = 1.0f;
#pragma unroll
        for (int q = 0; q < 6; ++q)
            A *= ((base >> (7 - q)) & 1) ? s[q] : c[q];

        float ar[4], ai[4];
        const int dlut[4] = {0, 1, 3, 2};
#pragma unroll
        for (int k = 0; k < 4; ++k) {
            int t = b3 ^ dlut[k];
            float f6 = (t & 2) ? s[6] : c[6];
            float f7 = (t & 1) ? s[7] : c[7];
            float a = A * f6 * f7;
            // RZ layer 0 on a real amplitude:
            ar[k] = a * p0r[k];
            ai[k] = a * p0i[k];
        }

        // ---- layer 1 RY: butterflies over lane bits (q0..5) ----
#pragma unroll
        for (int q = 0; q < 6; ++q) {
            const int   mask = 1 << (5 - q);
            const int   bit  = (lane >> (5 - q)) & 1;
            const float sg   = bit ? s[q] : -s[q];
            const float cc   = c[q];
#pragma unroll
            for (int k = 0; k < 4; ++k) {
                float pr = __shfl_xor(ar[k], mask, 64);
                float pi = __shfl_xor(ai[k], mask, 64);
                ar[k] = cc * ar[k] + sg * pr;
                ai[k] = cc * ai[k] + sg * pi;
            }
        }
        {   // q=6: in-lane pairs (0,2),(1,3)
            const float c6 = c[6], s6 = s[6];
            float n0r = c6*ar[0] - s6*ar[2], n0i = c6*ai[0] - s6*ai[2];
            float n2r = s6*ar[0] + c6*ar[2], n2i = s6*ai[0] + c6*ai[2];
            float n1r = c6*ar[1] - s6*ar[3], n1i = c6*ai[1] - s6*ai[3];
            float n3r = s6*ar[1] + c6*ar[3], n3i = s6*ai[1] + c6*ai[3];
            ar[0]=n0r; ai[0]=n0i; ar[2]=n2r; ai[2]=n2i;
            ar[1]=n1r; ai[1]=n1i; ar[3]=n3r; ai[3]=n3i;
        }
        {   // q=7: in-lane pairs (0,1),(2,3)
            const float c7 = c[7], s7 = s[7];
            float n0r = c7*ar[0] - s7*ar[1], n0i = c7*ai[0] - s7*ai[1];
            float n1r = s7*ar[0] + c7*ar[1], n1i = s7*ai[0] + c7*ai[1];
            float n2r = c7*ar[2] - s7*ar[3], n2i = c7*ai[2] - s7*ai[3];
            float n3r = s7*ar[2] + c7*ar[3], n3i = s7*ai[2] + c7*ai[3];
            ar[0]=n0r; ai[0]=n0i; ar[1]=n1r; ai[1]=n1i;
            ar[2]=n2r; ai[2]=n2i; ar[3]=n3r; ai[3]=n3i;
        }

        // ---- CNOT perm (layer 1) via LDS gather ----
        __syncthreads();
#pragma unroll
        for (int k = 0; k < 4; ++k)
            buf[w][(lane << 2) | k] = make_float2(ar[k], ai[k]);
        __syncthreads();
#pragma unroll
        for (int k = 0; k < 4; ++k) {
            float2 t = buf[w][base ^ dlut[k]];
            ar[k] = t.x; ai[k] = t.y;
        }

        // ---- RZ layer 1 (complex state, precomputed factors) ----
#pragma unroll
        for (int k = 0; k < 4; ++k) {
            float nr = ar[k]*p1r[k] - ai[k]*p1i[k];
            float ni = ar[k]*p1i[k] + ai[k]*p1r[k];
            ar[k] = nr; ai[k] = ni;
        }

        if (which == 0) {
#pragma unroll
            for (int k = 0; k < 4; ++k) { sxr[k]=ar[k]; sxi[k]=ai[k]; }
        } else {
#pragma unroll
            for (int k = 0; k < 4; ++k) { syr[k]=ar[k]; syi[k]=ai[k]; }
        }
    }

    // overlap = sum_i conj(sx_i)*sy_i ; out = |overlap|^2
    float re = 0.0f, im = 0.0f;
#pragma unroll
    for (int k = 0; k < 4; ++k) {
        re += sxr[k]*syr[k] + sxi[k]*syi[k];
        im += sxr[k]*syi[k] - sxi[k]*syr[k];
    }
#pragma unroll
    for (int m = 32; m >= 1; m >>= 1) {
        re += __shfl_xor(re, m, 64);
        im += __shfl_xor(im, m, 64);
    }
    if (lane == 0) out[b] = re*re + im*im;
}

extern "C" void kernel_launch(void* const* d_in, const int* in_sizes, int n_in,
                              void* d_out, int out_size, void* d_ws, size_t ws_size,
                              hipStream_t stream) {
    const float* x      = (const float*)d_in[0];
    const float* y      = (const float*)d_in[1];
    const float* params = (const float*)d_in[2];
    float* out = (float*)d_out;
    const int B = in_sizes[0] / 8;          // 16384
    const int blocks = (B + 3) / 4;         // 4 waves (batch elems) per block
    qkm_kernel<<<blocks, 256, 0, stream>>>(x, y, params, out, B);
}

// Round 3
// 9.720 us; speedup vs baseline: 5.1437x; 3.0374x over previous
//
#include <hip/hip_runtime.h>

// Quantum kernel method, algebraically collapsed.
//
// sx = RZ1·P·RY(x)·RZ0·P·RY(x)|0>, sy likewise. In <sx|sy>, RZ1 and the outer
// P cancel (same diagonal / same permutation on both states):
//   <sx|sy> = <px| P^T RZ0^H [RY(x)^H RY(y)] RZ0 P |py>
// with |px>=RY(x)|0>, |py>=RY(y)|0> product states (real), and
//   RZ0^H (⊗_q RY(y_q-x_q)) RZ0 = ⊗_q G_q,
//   G_q = [[cd, -sd e^{i phi_q}], [sd e^{-i phi_q}, cd]],
//   cd = cos((y_q-x_q)/2), sd = sin((y_q-x_q)/2), phi_q = params[0,q].
// P is GF(2)-linear: bit_n(sigma(i)) = i_n ^ i_{n+1} (i_8=0), so P|prod> is a
// bond-2 MPS and the overlap is a 2x2-complex transfer-matrix chain over the
// 8 bits n=7..0 (bit n holds qubit q=7-n):
//   W_7[i][m] = fx(i) G[i,m] fy(m)
//   W_n[i][m] = G_n[i,m] * sum_{i',m'} fx_n(i^i') fy_n(m^m') W_{n+1}[i'][m']
//   overlap   = sum_{i,m} W_0[i][m];  out = |overlap|^2.
// One lane per batch element: ~350 VALU ops, no LDS, no shuffles, no barriers.

__global__ __launch_bounds__(64) void qkm_kernel(
    const float* __restrict__ x, const float* __restrict__ y,
    const float* __restrict__ params, float* __restrict__ out, int B)
{
    int b = (int)(blockIdx.x * 64 + threadIdx.x);
    if (b >= B) return;

    const float4* xv = (const float4*)(x + (size_t)b * 8);
    const float4* yv = (const float4*)(y + (size_t)b * 8);
    float4 x0 = xv[0], x1 = xv[1], y0 = yv[0], y1 = yv[1];
    float xs[8] = {x0.x, x0.y, x0.z, x0.w, x1.x, x1.y, x1.z, x1.w};
    float ys[8] = {y0.x, y0.y, y0.z, y0.w, y1.x, y1.y, y1.z, y1.w};

    // half-angle cos/sin of x,y per qubit q
    float cx[8], sx[8], cy[8], sy[8];
#pragma unroll
    for (int q = 0; q < 8; ++q) {
        cx[q] = __cosf(0.5f * xs[q]);
        sx[q] = __sinf(0.5f * xs[q]);
        cy[q] = __cosf(0.5f * ys[q]);
        sy[q] = __sinf(0.5f * ys[q]);
    }

    // G_q entries: cd = cos((y-x)/2), sd = sin((y-x)/2);
    // gu = sd*cos(phi), gv = sd*sin(phi); G01 = (-gu,-gv), G10 = (gu,-gv).
    float cd[8], gu[8], gv[8];
#pragma unroll
    for (int q = 0; q < 8; ++q) {
        float cdd = cx[q] * cy[q] + sx[q] * sy[q];
        float sdd = sy[q] * cx[q] - cy[q] * sx[q];
        float ph  = params[q];            // params[0][q]; params[1][*] cancels
        float cp  = __cosf(ph);
        float sp  = __sinf(ph);
        cd[q] = cdd;
        gu[q] = sdd * cp;
        gv[q] = sdd * sp;
    }

    // chain over bits n=7..0  <=>  qubits q = 7-n = 0..7
    // init with q=0 (n=7): W[i][m] = fx(i) * G0[i,m] * fy(m)
    float w00r = cx[0] * cd[0] * cy[0], w00i = 0.0f;
    float t01  = cx[0] * sy[0];
    float w01r = -gu[0] * t01,          w01i = -gv[0] * t01;
    float t10  = sx[0] * cy[0];
    float w10r =  gu[0] * t10,          w10i = -gv[0] * t10;
    float w11r = sx[0] * cd[0] * sy[0], w11i = 0.0f;

#pragma unroll
    for (int q = 1; q < 8; ++q) {
        const float f0 = cx[q], f1 = sx[q], g0 = cy[q], g1 = sy[q];
        // A[i][m'] = sum_{i'} fx(i^i') W[i'][m']   (mix row index)
        float a00r = f0 * w00r + f1 * w10r, a00i = f0 * w00i + f1 * w10i;
        float a01r = f0 * w01r + f1 * w11r, a01i = f0 * w01i + f1 * w11i;
        float a10r = f1 * w00r + f0 * w10r, a10i = f1 * w00i + f0 * w10i;
        float a11r = f1 * w01r + f0 * w11r, a11i = f1 * w01i + f0 * w11i;
        // B[i][m] = sum_{m'} fy(m^m') A[i][m']    (mix col index)
        float b00r = g0 * a00r + g1 * a01r, b00i = g0 * a00i + g1 * a01i;
        float b01r = g1 * a00r + g0 * a01r, b01i = g1 * a00i + g0 * a01i;
        float b10r = g0 * a10r + g1 * a11r, b10i = g0 * a10i + g1 * a11i;
        float b11r = g1 * a10r + g0 * a11r, b11i = g1 * a10i + g0 * a11i;
        // W = G ∘ B (elementwise complex)
        w00r = cd[q] * b00r;                  w00i = cd[q] * b00i;
        w11r = cd[q] * b11r;                  w11i = cd[q] * b11i;
        w01r = -gu[q] * b01r + gv[q] * b01i;  w01i = -gu[q] * b01i - gv[q] * b01r;
        w10r =  gu[q] * b10r + gv[q] * b10i;  w10i =  gu[q] * b10i - gv[q] * b10r;
    }

    float re = w00r + w01r + w10r + w11r;
    float im = w00i + w01i + w10i + w11i;
    out[b] = re * re + im * im;
}

extern "C" void kernel_launch(void* const* d_in, const int* in_sizes, int n_in,
                              void* d_out, int out_size, void* d_ws, size_t ws_size,
                              hipStream_t stream) {
    const float* x      = (const float*)d_in[0];
    const float* y      = (const float*)d_in[1];
    const float* params = (const float*)d_in[2];
    float* out = (float*)d_out;
    const int B = in_sizes[0] / 8;          // 16384
    const int blocks = (B + 63) / 64;       // one lane per batch element
    qkm_kernel<<<blocks, 64, 0, stream>>>(x, y, params, out, B);
}

// Round 4
// 9.716 us; speedup vs baseline: 5.1461x; 1.0005x over previous
//
#include <hip/hip_runtime.h>

// Quantum kernel method, algebraically collapsed (see R3 derivation):
//   <sx|sy> = <px| P^T RZ0^H [RY(x)^H RY(y)] RZ0 P |py>
// RZ1 and the outer CNOT-perm cancel between the two states; the permuted
// product states form a bond-2 MPS, so the 256-dim overlap collapses to an
// 8-step 2x2-complex transfer-matrix chain. One lane per batch element,
// ~300 VALU ops, no LDS / shuffles / barriers.
// R4: shave-only probe (branchless clamp, no early return) to confirm the
// measured time is launch-overhead floor, not kernel execution.

__global__ __launch_bounds__(64) void qkm_kernel(
    const float* __restrict__ x, const float* __restrict__ y,
    const float* __restrict__ params, float* __restrict__ out, int B)
{
    int b = (int)(blockIdx.x * 64 + threadIdx.x);
    b = b < B ? b : B - 1;                 // branchless clamp, no divergence

    const float4* xv = (const float4*)(x + (size_t)b * 8);
    const float4* yv = (const float4*)(y + (size_t)b * 8);
    float4 x0 = xv[0], x1 = xv[1], y0 = yv[0], y1 = yv[1];
    float xs[8] = {x0.x, x0.y, x0.z, x0.w, x1.x, x1.y, x1.z, x1.w};
    float ys[8] = {y0.x, y0.y, y0.z, y0.w, y1.x, y1.y, y1.z, y1.w};

    float cx[8], sx[8], cy[8], sy[8];
#pragma unroll
    for (int q = 0; q < 8; ++q) {
        cx[q] = __cosf(0.5f * xs[q]);
        sx[q] = __sinf(0.5f * xs[q]);
        cy[q] = __cosf(0.5f * ys[q]);
        sy[q] = __sinf(0.5f * ys[q]);
    }

    // G_q: cd = cos((y-x)/2), sd = sin((y-x)/2), phi = params[0][q];
    // gu = sd*cos(phi), gv = sd*sin(phi); G01=(-gu,-gv), G10=(gu,-gv).
    float cd[8], gu[8], gv[8];
#pragma unroll
    for (int q = 0; q < 8; ++q) {
        float cdd = fmaf(cx[q], cy[q],  sx[q] * sy[q]);
        float sdd = fmaf(sy[q], cx[q], -cy[q] * sx[q]);
        float ph  = params[q];             // params[1][*] cancels exactly
        cd[q] = cdd;
        gu[q] = sdd * __cosf(ph);
        gv[q] = sdd * __sinf(ph);
    }

    // chain over bits n=7..0 (qubit q=7-n); init with q=0:
    float w00r = cx[0] * cd[0] * cy[0], w00i = 0.0f;
    float t01  = cx[0] * sy[0];
    float w01r = -gu[0] * t01,          w01i = -gv[0] * t01;
    float t10  = sx[0] * cy[0];
    float w10r =  gu[0] * t10,          w10i = -gv[0] * t10;
    float w11r = sx[0] * cd[0] * sy[0], w11i = 0.0f;

#pragma unroll
    for (int q = 1; q < 8; ++q) {
        const float f0 = cx[q], f1 = sx[q], g0 = cy[q], g1 = sy[q];
        float a00r = fmaf(f0, w00r, f1 * w10r), a00i = fmaf(f0, w00i, f1 * w10i);
        float a01r = fmaf(f0, w01r, f1 * w11r), a01i = fmaf(f0, w01i, f1 * w11i);
        float a10r = fmaf(f1, w00r, f0 * w10r), a10i = fmaf(f1, w00i, f0 * w10i);
        float a11r = fmaf(f1, w01r, f0 * w11r), a11i = fmaf(f1, w01i, f0 * w11i);
        float b00r = fmaf(g0, a00r, g1 * a01r), b00i = fmaf(g0, a00i, g1 * a01i);
        float b01r = fmaf(g1, a00r, g0 * a01r), b01i = fmaf(g1, a00i, g0 * a01i);
        float b10r = fmaf(g0, a10r, g1 * a11r), b10i = fmaf(g0, a10i, g1 * a11i);
        float b11r = fmaf(g1, a10r, g0 * a11r), b11i = fmaf(g1, a10i, g0 * a11i);
        w00r = cd[q] * b00r;                        w00i = cd[q] * b00i;
        w11r = cd[q] * b11r;                        w11i = cd[q] * b11i;
        w01r = fmaf(-gu[q], b01r,  gv[q] * b01i);   w01i = fmaf(-gu[q], b01i, -gv[q] * b01r);
        w10r = fmaf( gu[q], b10r,  gv[q] * b10i);   w10i = fmaf( gu[q], b10i, -gv[q] * b10r);
    }

    float re = (w00r + w01r) + (w10r + w11r);
    float im = (w00i + w01i) + (w10i + w11i);
    out[b] = fmaf(re, re, im * im);
}

extern "C" void kernel_launch(void* const* d_in, const int* in_sizes, int n_in,
                              void* d_out, int out_size, void* d_ws, size_t ws_size,
                              hipStream_t stream) {
    const float* x      = (const float*)d_in[0];
    const float* y      = (const float*)d_in[1];
    const float* params = (const float*)d_in[2];
    float* out = (float*)d_out;
    const int B = in_sizes[0] / 8;          // 16384
    const int blocks = (B + 63) / 64;       // one lane per batch element
    qkm_kernel<<<blocks, 64, 0, stream>>>(x, y, params, out, B);
}